// Round 3
// baseline (28.645 us; speedup 1.0000x reference)
//
#include <hip/hip_runtime.h>

#define NPART  8192
#define NSPLIT 64                 // j-splits per i-tile
#define JCHUNK (NPART / NSPLIT)   // 128 j's per block
#define ITILES (NPART / 256)      // 32 i-tiles

// Fused pair + reduce kernel (single dispatch, last-block-done reduction).
//
// Cubic spline identity: w(q) = 2*max(1-q,0)^3 - max(1-2q,0)^3
//   (== 1-6q^2+6q^3 for q<=0.5; 2(1-q)^3 for 0.5<q<=1; 0 for q>1).
// With q = r/h, h=0.1: a = max(1-10r,0), b = max(1-20r,0), w = 2a^3 - b^3.
// w == 0 exactly for r^2 > 0.01, so a wave skips sqrt+poly when no lane has
// any of its 4 candidate pairs inside the cutoff (hit prob ~2.5%/group).
//
// Cross-block handoff: partials are published with system-scope relaxed
// atomic stores (sc0/sc1 -> coherence point = shared L3, valid cross-XCD);
// the s_waitcnt vmcnt(0) before __syncthreads' s_barrier guarantees every
// wave's stores completed before thread 0 signals the per-tile counter
// (agent-scope RMW). The 64th arrival re-reads all partials in fixed order
// k=0..63 -> bitwise-deterministic output regardless of which block is last.
__global__ __launch_bounds__(256) void sph_fused(const float* __restrict__ pos,
                                                 float* __restrict__ ws,
                                                 int* __restrict__ cnt,
                                                 float* __restrict__ out) {
    __shared__ float sj[JCHUNK * 3];
    __shared__ int lastflag;

    const int tid = threadIdx.x;
    const int bi  = blockIdx.x;            // i-tile  [0,32)
    const int bj  = blockIdx.y;            // j-split [0,64)
    const int i   = bi * 256 + tid;
    const int j0  = bj * JCHUNK;

    // Stage j-tile (128 pts = 1536 B) with float4 loads; byte offset
    // 12*j0 is 16B-aligned since JCHUNK=128.
    {
        const float4* src = (const float4*)(pos + (size_t)j0 * 3);
        float4*       dst = (float4*)sj;
        if (tid < JCHUNK * 3 / 4) dst[tid] = src[tid];   // 96 threads
    }
    __syncthreads();

    const float xi = pos[3 * i + 0];
    const float yi = pos[3 * i + 1];
    const float zi = pos[3 * i + 2];

    const float RCUT2 = 0.0100001f;  // (h=0.1)^2 + margin; w==0 beyond
    float acc1 = 0.0f;               // sum a^3
    float acc2 = 0.0f;               // sum b^3

    for (int j = 0; j < JCHUNK; j += 4) {
        // 4 j-positions = 12 floats = 3 LDS float4 broadcast reads
        const float4 p0 = *(const float4*)&sj[3 * j + 0];
        const float4 p1 = *(const float4*)&sj[3 * j + 4];
        const float4 p2 = *(const float4*)&sj[3 * j + 8];

        const float dx0 = p0.x - xi, dy0 = p0.y - yi, dz0 = p0.z - zi;
        const float dx1 = p0.w - xi, dy1 = p1.x - yi, dz1 = p1.y - zi;
        const float dx2 = p1.z - xi, dy2 = p1.w - yi, dz2 = p2.x - zi;
        const float dx3 = p2.y - xi, dy3 = p2.z - yi, dz3 = p2.w - zi;

        const float d20 = fmaf(dx0, dx0, fmaf(dy0, dy0, fmaf(dz0, dz0, 1e-10f)));
        const float d21 = fmaf(dx1, dx1, fmaf(dy1, dy1, fmaf(dz1, dz1, 1e-10f)));
        const float d22 = fmaf(dx2, dx2, fmaf(dy2, dy2, fmaf(dz2, dz2, 1e-10f)));
        const float d23 = fmaf(dx3, dx3, fmaf(dy3, dy3, fmaf(dz3, dz3, 1e-10f)));

        const float m = fminf(fminf(d20, d21), fminf(d22, d23));
        if (__any(m <= RCUT2)) {
            {
                const float r = __builtin_amdgcn_sqrtf(d20);
                const float a = fmaxf(fmaf(-10.0f, r, 1.0f), 0.0f);
                const float b = fmaxf(fmaf(-20.0f, r, 1.0f), 0.0f);
                acc1 = fmaf(a * a, a, acc1);
                acc2 = fmaf(b * b, b, acc2);
            }
            {
                const float r = __builtin_amdgcn_sqrtf(d21);
                const float a = fmaxf(fmaf(-10.0f, r, 1.0f), 0.0f);
                const float b = fmaxf(fmaf(-20.0f, r, 1.0f), 0.0f);
                acc1 = fmaf(a * a, a, acc1);
                acc2 = fmaf(b * b, b, acc2);
            }
            {
                const float r = __builtin_amdgcn_sqrtf(d22);
                const float a = fmaxf(fmaf(-10.0f, r, 1.0f), 0.0f);
                const float b = fmaxf(fmaf(-20.0f, r, 1.0f), 0.0f);
                acc1 = fmaf(a * a, a, acc1);
                acc2 = fmaf(b * b, b, acc2);
            }
            {
                const float r = __builtin_amdgcn_sqrtf(d23);
                const float a = fmaxf(fmaf(-10.0f, r, 1.0f), 0.0f);
                const float b = fmaxf(fmaf(-20.0f, r, 1.0f), 0.0f);
                acc1 = fmaf(a * a, a, acc1);
                acc2 = fmaf(b * b, b, acc2);
            }
        }
    }

    // Publish this block's partial to the coherence point (bypass local L1/L2).
    const float partial = fmaf(2.0f, acc1, -acc2);
    __hip_atomic_store(&ws[(size_t)bj * NPART + i], partial,
                       __ATOMIC_RELAXED, __HIP_MEMORY_SCOPE_SYSTEM);

    // s_waitcnt vmcnt(0) before the barrier => all waves' stores complete.
    __syncthreads();

    if (tid == 0) {
        int old = __hip_atomic_fetch_add(&cnt[bi], 1,
                                         __ATOMIC_RELAXED, __HIP_MEMORY_SCOPE_AGENT);
        lastflag = (old == NSPLIT - 1);
    }
    __syncthreads();

    if (lastflag) {
        // Last arrival for this i-tile: fixed-order reduce -> deterministic.
        float s = 0.0f;
        for (int k = 0; k < NSPLIT; ++k)
            s += __hip_atomic_load(&ws[(size_t)k * NPART + i],
                                   __ATOMIC_RELAXED, __HIP_MEMORY_SCOPE_SYSTEM);
        const float norm = (float)(8.0 / (3.14159265 * 0.1 * 0.1 * 0.1));
        out[i] = s * norm;
    }
}

extern "C" void kernel_launch(void* const* d_in, const int* in_sizes, int n_in,
                              void* d_out, int out_size, void* d_ws, size_t ws_size,
                              hipStream_t stream) {
    const float* pos = (const float*)d_in[0];
    float*       out = (float*)d_out;
    float*       ws  = (float*)d_ws;
    int*         cnt = (int*)(ws + (size_t)NSPLIT * NPART);  // 32 ints after partials

    // Zero the per-tile arrival counters each launch (128 B, graph-capturable).
    hipMemsetAsync(cnt, 0, ITILES * sizeof(int), stream);

    dim3 grid(ITILES, NSPLIT);   // 2048 blocks = 8 blocks/CU on 256 CUs
    sph_fused<<<grid, 256, 0, stream>>>(pos, ws, cnt, out);
}